// Round 13
// baseline (301.114 us; speedup 1.0000x reference)
//
#include <hip/hip_runtime.h>
#include <math.h>

#define N_NODES 50000
#define N_EDGES 800000
#define IN_CH   256
#define OUT_CH  64
#define HEADS   4
#define NEG_SLOPE 0.2f
#define NCOLS   320           // W (256) || W_res (64)
#define NTILES  20            // NCOLS / 16
#define NKK     8             // IN_CH / 32
#define PACK_BLOCKS 40        // NKK*NTILES*64 / 256
#define GEMM_BLOCKS 782       // (N_NODES+63)/64
#define NBINS   782           // 64-dst bins (bin = dst>>6); 782*64 = 50048
#define P1_BLOCKS 256         // edge-partition blocks
#define EPB     3125          // edges per partition block = N_EDGES/256
#define SORT_CAP 1600         // max records per bin (mean 1023, sd 32; 18 sigma)
// R13 schedule: 3 dispatches (was 5). Laws from R0-R12:
//  - gemm costs ~65us PER DISPATCH regardless of block count -> never chunk
//  - fused independent halves run at max(), not sum() -> hide CSR under gemm
//  - each extra dispatch costs ~10us launch gap -> minimize launches
// D1 prep: hist || pack_B. D2 gemm_part2: part (self-sufficient: re-derives
// binscan from raw M, hidden under gemm) || full gemm. D3 agg2: per-bin
// fused LDS-sort (scatter) + aggregate.

typedef __attribute__((ext_vector_type(8))) short short8;
typedef __attribute__((ext_vector_type(4))) float f32x4;

__device__ __forceinline__ float lrelu(float v) {
    return v > 0.f ? v : NEG_SLOPE * v;
}
__device__ __forceinline__ unsigned bf16_rne(float f) {
    unsigned u = __float_as_uint(f);
    return (u + 0x7FFFu + ((u >> 16) & 1u)) >> 16;
}
__device__ __forceinline__ unsigned pack2(float lo, float hi) {
    return bf16_rne(lo) | (bf16_rne(hi) << 16);
}
__device__ __forceinline__ float bflo(unsigned u) { return __uint_as_float(u << 16); }
__device__ __forceinline__ float bfhi(unsigned u) { return __uint_as_float(u & 0xFFFF0000u); }
__device__ __forceinline__ short8 as_short8(uint4 u) {
    union { uint4 u4; short8 s8; } cv; cv.u4 = u; return cv.s8;
}

// ---------------------------------------------------------------------------
// D1 prep: fused independent halves.
//   blocks [0, P1_BLOCKS)        : histogram (lean shape, 3.1 KB LDS)
//   blocks [P1_BLOCKS,+PACK)     : pack_B
// ---------------------------------------------------------------------------
__global__ __launch_bounds__(256) void prep(
    const int* __restrict__ ei, int* __restrict__ M,
    const float* __restrict__ W, const float* __restrict__ Wres,
    uint4* __restrict__ Bp)
{
    __shared__ int lh[NBINS];
    const int t = threadIdx.x;

    if (blockIdx.x < P1_BLOCKS) {
        const int blk = blockIdx.x;
        for (int b = t; b < NBINS; b += 256) lh[b] = 0;
        __syncthreads();
        const int e0 = blk * EPB;
        #pragma unroll
        for (int r = 0; r < 13; ++r) {
            const int idx = (r << 8) + t;
            if (idx < EPB)
                atomicAdd(&lh[ei[N_EDGES + e0 + idx] >> 6], 1);
        }
        __syncthreads();
        for (int b = t; b < NBINS; b += 256)
            M[(size_t)b * P1_BLOCKS + blk] = lh[b];
        return;
    }

    const int idx  = (blockIdx.x - P1_BLOCKS) * 256 + t;   // 0..10239
    const int kk   = idx / (NTILES * 64);
    const int rem  = idx - kk * (NTILES * 64);
    const int tt   = rem >> 6;
    const int lane = rem & 63;
    const int colL = lane & 15, quad = lane >> 4;
    const int col  = tt * 16 + colL;
    const int k0   = kk * 32 + quad * 8;
    float v[8];
    #pragma unroll
    for (int j = 0; j < 8; ++j) {
        const int k = k0 + j;
        v[j] = (col < IN_CH) ? W[(size_t)k * IN_CH + col]
                             : Wres[(size_t)k * OUT_CH + (col - IN_CH)];
    }
    uint4 u;
    u.x = pack2(v[0], v[1]); u.y = pack2(v[2], v[3]);
    u.z = pack2(v[4], v[5]); u.w = pack2(v[6], v[7]);
    Bp[(kk * NTILES + tt) * 64 + lane] = u;
}

// ---------------------------------------------------------------------------
// gemm_body: R6/R10's proven 64-row/256-thr MFMA transform + fused logits.
// Wave wv owns col-tiles {wv,4+wv,8+wv,12+wv,16+wv} over 4 row-groups.
// ---------------------------------------------------------------------------
__device__ __forceinline__ void gemm_body(
    const int n0, const float* __restrict__ x, const uint4* __restrict__ Bp,
    uint2* __restrict__ xw2, float* __restrict__ xres,
    const float* __restrict__ attS, const float* __restrict__ attD,
    float* __restrict__ asrc, float* __restrict__ adst,
    uint4* Alds, float (*logS)[HEADS], float (*logD)[HEADS])
{
    const int tid = threadIdx.x;

    logS[tid >> 2][tid & 3] = 0.f;
    logD[tid >> 2][tid & 3] = 0.f;

    #pragma unroll
    for (int i = 0; i < 8; ++i) {
        const int e    = i * 256 + tid;
        const int g    = e >> 9;
        const int kk   = (e >> 6) & 7;
        const int lane = e & 63;
        const int cL   = lane & 15, qd = lane >> 4;
        const int row  = n0 + g * 16 + cL;
        const int k0   = kk * 32 + qd * 8;
        uint4 u = make_uint4(0u, 0u, 0u, 0u);
        if (row < N_NODES) {
            const float4 a = *reinterpret_cast<const float4*>(x + (size_t)row * IN_CH + k0);
            const float4 b = *reinterpret_cast<const float4*>(x + (size_t)row * IN_CH + k0 + 4);
            u.x = pack2(a.x, a.y); u.y = pack2(a.z, a.w);
            u.z = pack2(b.x, b.y); u.w = pack2(b.z, b.w);
        }
        Alds[(g * NKK + kk) * 64 + lane] = u;
    }
    __syncthreads();

    const int lane = tid & 63;
    const int wv   = tid >> 6;
    const int colL = lane & 15, quad = lane >> 4;

    f32x4 acc[4][5];
    #pragma unroll
    for (int rg = 0; rg < 4; ++rg)
        #pragma unroll
        for (int j = 0; j < 5; ++j) acc[rg][j] = (f32x4){0.f, 0.f, 0.f, 0.f};

    for (int kk = 0; kk < NKK; ++kk) {
        uint4 bu[5];
        #pragma unroll
        for (int j = 0; j < 5; ++j)
            bu[j] = Bp[(kk * NTILES + j * 4 + wv) * 64 + lane];
        #pragma unroll
        for (int rg = 0; rg < 4; ++rg) {
            const short8 a = as_short8(Alds[(rg * NKK + kk) * 64 + lane]);
            #pragma unroll
            for (int j = 0; j < 5; ++j)
                acc[rg][j] = __builtin_amdgcn_mfma_f32_16x16x32_bf16(
                    a, as_short8(bu[j]), acc[rg][j], 0, 0, 0);
        }
    }

    #pragma unroll
    for (int rg = 0; rg < 4; ++rg) {
        #pragma unroll
        for (int r = 0; r < 4; ++r) {
            const int row = n0 + rg * 16 + quad * 4 + r;
            if (row < N_NODES) {
                xw2[(size_t)row * 64 + wv * 16 + colL] = make_uint2(
                    pack2(acc[rg][0][r], acc[rg][1][r]),
                    pack2(acc[rg][2][r], acc[rg][3][r]));
                xres[(size_t)row * OUT_CH + wv * 16 + colL] = acc[rg][4][r];
            }
        }
    }

    float aSr[HEADS], aDr[HEADS];
    #pragma unroll
    for (int h = 0; h < HEADS; ++h) {
        aSr[h] = attS[h * 64 + wv * 16 + colL];
        aDr[h] = attD[h * 64 + wv * 16 + colL];
    }
    #pragma unroll
    for (int rg = 0; rg < 4; ++rg) {
        #pragma unroll
        for (int h = 0; h < HEADS; ++h) {
            #pragma unroll
            for (int r = 0; r < 4; ++r) {
                float vS = acc[rg][h][r] * aSr[h];
                float vD = acc[rg][h][r] * aDr[h];
                #pragma unroll
                for (int m = 1; m < 16; m <<= 1) {      // stays within quad
                    vS += __shfl_xor(vS, m);
                    vD += __shfl_xor(vD, m);
                }
                if (colL == 0) {
                    atomicAdd(&logS[rg * 16 + quad * 4 + r][h], vS);
                    atomicAdd(&logD[rg * 16 + quad * 4 + r][h], vD);
                }
            }
        }
    }
    __syncthreads();
    {
        const int rl = tid >> 2, h = tid & 3;
        const int row = n0 + rl;
        if (row < N_NODES) {
            asrc[(size_t)row * HEADS + h] = logS[rl][h];
            adst[(size_t)row * HEADS + h] = logD[rl][h];
        }
    }
}

// ---------------------------------------------------------------------------
// D2 gemm_part2: fused — blocks [0,256) partition (SELF-SUFFICIENT: derives
// row totals + own-column prefix from RAW M in-block, replacing the old
// binscan dispatch — 4 coalesced reads + 2 shfl-reduces per bin, L2-hot,
// hidden under the gemm's fixed ~65us); blocks [256,+782) the FULL gemm.
// Block 0 publishes binStart/binCnt for agg2.
// ---------------------------------------------------------------------------
__global__ __launch_bounds__(256) void gemm_part2(
    const float* __restrict__ x, const uint4* __restrict__ Bp,
    uint2* __restrict__ xw2, float* __restrict__ xres,
    const float* __restrict__ attS, const float* __restrict__ attD,
    float* __restrict__ asrc, float* __restrict__ adst,
    const int* __restrict__ ei, const int* __restrict__ M,
    int* __restrict__ binCnt, int* __restrict__ binStart,
    unsigned* __restrict__ mid)
{
    __shared__ uint4 Alds[4 * NKK * 64];   // 32 KB (aliased by part branch)
    __shared__ float logS[64][HEADS];
    __shared__ float logD[64][HEADS];
    const int t = threadIdx.x, lane = t & 63, wv = t >> 6;

    if (blockIdx.x < P1_BLOCKS) {
        int* bc    = (int*)Alds;           // [782] row totals
        int* bs    = bc + NBINS;           // [782] bin starts
        int* baseL = bs + NBINS;           // [782] own-column prefix
        int* lh    = baseL + NBINS;        // [782] running positions
        int* ws    = lh + NBINS;           // [4]
        const int blk = blockIdx.x;

        // derive totals + own prefix from RAW M (replaces binscan dispatch)
        for (int b = wv; b < NBINS; b += 4) {
            const int* rowp = M + (size_t)b * P1_BLOCKS;
            int tot = 0, pre = 0;
            #pragma unroll
            for (int c4 = 0; c4 < 4; ++c4) {
                const int c = (c4 << 6) + lane;
                const int v = rowp[c];
                tot += v;
                if (c < blk) pre += v;
            }
            #pragma unroll
            for (int o = 32; o >= 1; o >>= 1) {
                tot += __shfl_xor(tot, o);
                pre += __shfl_xor(pre, o);
            }
            if (lane == 0) { bc[b] = tot; baseL[b] = pre; }
        }
        for (int b = t; b < NBINS; b += 256) lh[b] = 0;
        __syncthreads();

        // exclusive bin-scan of bc -> bs, 4 chunks of 256 with carry
        int carry = 0;
        for (int c = 0; c < 4; ++c) {
            const int i = (c << 8) + t;
            const int v = (i < NBINS) ? bc[i] : 0;
            int sc = v;
            #pragma unroll
            for (int o = 1; o < 64; o <<= 1) {
                const int n = __shfl_up(sc, o);
                if (lane >= o) sc += n;
            }
            if (lane == 63) ws[wv] = sc;
            __syncthreads();
            int prefix = 0;
            for (int j = 0; j < wv; ++j) prefix += ws[j];
            if (i < NBINS) bs[i] = carry + prefix + sc - v;
            carry += ws[0] + ws[1] + ws[2] + ws[3];
            __syncthreads();   // protect ws before next chunk rewrites it
        }
        for (int b = t; b < NBINS; b += 256) baseL[b] += bs[b];
        if (blk == 0) {
            for (int b = t; b < NBINS; b += 256) {
                binStart[b] = bs[b];
                binCnt[b]   = bc[b];
            }
        }
        __syncthreads();

        const int e0 = blk * EPB;
        #pragma unroll
        for (int r = 0; r < 13; ++r) {
            const int idx = (r << 8) + t;
            if (idx < EPB) {
                const int e = e0 + idx;
                const int d = ei[N_EDGES + e];
                const int b = d >> 6;
                const int pos = atomicAdd(&lh[b], 1);
                mid[baseL[b] + pos] = ((unsigned)(d & 63) << 17) | (unsigned)ei[e];
            }
        }
        return;
    }
    gemm_body((blockIdx.x - P1_BLOCKS) * 64,
              x, Bp, xw2, xres, attS, attD, asrc, adst, Alds, logS, logD);
}

// ---------------------------------------------------------------------------
// D3 agg2: fused scatter + aggregate, one 512-thread block per 64-dst bin.
// Phase A (was scatter_fine2): count the bin's dsts, single-wave 64-scan,
// LDS-sort the ~1024 records into srt[] (no esrc global round-trip).
// Phase B (R8's proven gather body): 8 waves x 8 dsts each; per dst the
// lane<->channel mapping and the uniform-addr xw2 dwordx2 gather are
// byte-identical to the 64.7us-measured aggregate. Concurrency preserved:
// 782 blocks x 8 waves all-resident ~= old 12500x4 average waves/CU, so the
// fabric-bound gather (FETCH 214 MB = 8 XCD x ~27 MB compulsory, ~450 GB/s
// per-XCD port) stays saturated.
// ---------------------------------------------------------------------------
__global__ __launch_bounds__(512) void agg2(
    const unsigned* __restrict__ mid, const int* __restrict__ binStart,
    const int* __restrict__ binCnt,
    const float* __restrict__ asrc, const float* __restrict__ adst,
    const uint2* __restrict__ xw2, const float* __restrict__ xres,
    const float* __restrict__ bias, float* __restrict__ out)
{
    __shared__ int c64[64];
    __shared__ int o64[64];
    __shared__ int srt[SORT_CAP];          // 6.4 KB
    __shared__ float4 wbuf[8][64];         // 8 KB
    __shared__ int    sbuf[8][64];         // 2 KB
    const int t = threadIdx.x, lane = t & 63, wv = t >> 6;   // wv 0..7
    const int b = blockIdx.x;
    const int base = binStart[b];
    const int n = binCnt[b];

    if (t < 64) c64[t] = 0;
    __syncthreads();

    for (int i = t; i < n; i += 512)
        atomicAdd(&c64[(int)(mid[base + i] >> 17)], 1);
    __syncthreads();

    if (t < 64) {                          // single-wave exclusive scan
        const int v = c64[t];
        int sc = v;
        #pragma unroll
        for (int o = 1; o < 64; o <<= 1) {
            const int nn = __shfl_up(sc, o);
            if (t >= o) sc += nn;
        }
        o64[t] = sc - v;
        c64[t] = 0;                        // reuse as running positions
    }
    __syncthreads();

    for (int i = t; i < n; i += 512) {
        const unsigned m = mid[base + i];
        const int dlo = (int)(m >> 17);
        const int pos = atomicAdd(&c64[dlo], 1);
        srt[o64[dlo] + pos] = (int)(m & 0x1FFFFu);
    }
    __syncthreads();                       // c64[dlo] == per-dst count again

    const char* xwB = (const char*)xw2;
    const int laneB = lane << 3;

    #pragma unroll 1
    for (int k = 0; k < 8; ++k) {
        const int dlo = wv * 8 + k;
        const int d = (b << 6) + dlo;
        if (d >= N_NODES) continue;        // tail bin
        const int off = o64[dlo];
        const int deg = c64[dlo];
        const float4 ad = *reinterpret_cast<const float4*>(adst + (size_t)d * 4);

        float dn0 = 0.f, dn1 = 0.f, dn2 = 0.f, dn3 = 0.f;
        float ac0 = 0.f, ac1 = 0.f, ac2 = 0.f, ac3 = 0.f;

        for (int bs0 = 0; bs0 < deg; bs0 += 64) {
            const int m = min(64, deg - bs0);
            if (lane < m) {
                const int s = srt[off + bs0 + lane];
                const float4 as = *reinterpret_cast<const float4*>(asrc + (size_t)s * 4);
                const float e0 = __expf(lrelu(as.x + ad.x));
                const float e1 = __expf(lrelu(as.y + ad.y));
                const float e2 = __expf(lrelu(as.z + ad.z));
                const float e3 = __expf(lrelu(as.w + ad.w));
                dn0 += e0; dn1 += e1; dn2 += e2; dn3 += e3;
                wbuf[wv][lane] = make_float4(e0, e1, e2, e3);
                sbuf[wv][lane] = s << 9;   // *512 B node row
            }
            int j = 0;
            for (; j + 4 <= m; j += 4) {
                uint2 v0 = *(const uint2*)(xwB + sbuf[wv][j]     + laneB);
                uint2 v1 = *(const uint2*)(xwB + sbuf[wv][j + 1] + laneB);
                uint2 v2 = *(const uint2*)(xwB + sbuf[wv][j + 2] + laneB);
                uint2 v3 = *(const uint2*)(xwB + sbuf[wv][j + 3] + laneB);
                {
                    const float4 w = wbuf[wv][j];
                    ac0 = fmaf(w.x, bflo(v0.x), ac0); ac1 = fmaf(w.y, bfhi(v0.x), ac1);
                    ac2 = fmaf(w.z, bflo(v0.y), ac2); ac3 = fmaf(w.w, bfhi(v0.y), ac3);
                }
                {
                    const float4 w = wbuf[wv][j + 1];
                    ac0 = fmaf(w.x, bflo(v1.x), ac0); ac1 = fmaf(w.y, bfhi(v1.x), ac1);
                    ac2 = fmaf(w.z, bflo(v1.y), ac2); ac3 = fmaf(w.w, bfhi(v1.y), ac3);
                }
                {
                    const float4 w = wbuf[wv][j + 2];
                    ac0 = fmaf(w.x, bflo(v2.x), ac0); ac1 = fmaf(w.y, bfhi(v2.x), ac1);
                    ac2 = fmaf(w.z, bflo(v2.y), ac2); ac3 = fmaf(w.w, bfhi(v2.y), ac3);
                }
                {
                    const float4 w = wbuf[wv][j + 3];
                    ac0 = fmaf(w.x, bflo(v3.x), ac0); ac1 = fmaf(w.y, bfhi(v3.x), ac1);
                    ac2 = fmaf(w.z, bflo(v3.y), ac2); ac3 = fmaf(w.w, bfhi(v3.y), ac3);
                }
            }
            for (; j < m; ++j) {
                const float4 w = wbuf[wv][j];
                const uint2 v = *(const uint2*)(xwB + sbuf[wv][j] + laneB);
                ac0 = fmaf(w.x, bflo(v.x), ac0);
                ac1 = fmaf(w.y, bfhi(v.x), ac1);
                ac2 = fmaf(w.z, bflo(v.y), ac2);
                ac3 = fmaf(w.w, bfhi(v.y), ac3);
            }
        }

        #pragma unroll
        for (int off2 = 32; off2 >= 1; off2 >>= 1) {
            dn0 += __shfl_xor(dn0, off2);
            dn1 += __shfl_xor(dn1, off2);
            dn2 += __shfl_xor(dn2, off2);
            dn3 += __shfl_xor(dn3, off2);
        }
        // self-loop
        const float4 asd = *reinterpret_cast<const float4*>(asrc + (size_t)d * 4);
        const float s0 = __expf(lrelu(asd.x + ad.x));
        const float s1 = __expf(lrelu(asd.y + ad.y));
        const float s2 = __expf(lrelu(asd.z + ad.z));
        const float s3 = __expf(lrelu(asd.w + ad.w));
        const uint2 u = xw2[(size_t)d * 64 + lane];
        ac0 = fmaf(s0, bflo(u.x), ac0); ac1 = fmaf(s1, bfhi(u.x), ac1);
        ac2 = fmaf(s2, bflo(u.y), ac2); ac3 = fmaf(s3, bfhi(u.y), ac3);
        const float i0 = 0.25f / (dn0 + s0);
        const float i1 = 0.25f / (dn1 + s1);
        const float i2 = 0.25f / (dn2 + s2);
        const float i3 = 0.25f / (dn3 + s3);
        const float v = ac0 * i0 + ac1 * i1 + ac2 * i2 + ac3 * i3
                      + bias[lane] + xres[(size_t)d * OUT_CH + lane];
        out[(size_t)d * OUT_CH + lane] = fmaxf(v, 0.f);
    }
}

extern "C" void kernel_launch(void* const* d_in, const int* in_sizes, int n_in,
                              void* d_out, int out_size, void* d_ws, size_t ws_size,
                              hipStream_t stream) {
    const float* x    = (const float*)d_in[0];
    const int*   ei   = (const int*)d_in[1];
    const float* W    = (const float*)d_in[2];
    const float* attS = (const float*)d_in[3];
    const float* attD = (const float*)d_in[4];
    const float* bias = (const float*)d_in[5];
    const float* Wres = (const float*)d_in[6];
    float* out = (float*)d_out;

    char* p = (char*)d_ws;
    uint4*    Bp      = (uint4*)p;    p += (size_t)NKK * NTILES * 64 * 16;  // 160 KB
    uint2*    xw2     = (uint2*)p;    p += (size_t)N_NODES * 64 * 8;        // 25.6 MB
    float*    xres    = (float*)p;    p += (size_t)N_NODES * OUT_CH * 4;    // 12.8 MB
    float*    asrc    = (float*)p;    p += (size_t)N_NODES * HEADS * 4;
    float*    adst    = (float*)p;    p += (size_t)N_NODES * HEADS * 4;
    int*      M       = (int*)p;      p += (size_t)NBINS * P1_BLOCKS * 4;   // 800 KB
    int*      binCnt  = (int*)p;      p += 1024 * 4;
    int*      binStart= (int*)p;      p += 1024 * 4;
    unsigned* mid     = (unsigned*)p; p += (size_t)N_EDGES * 4;             // 3.2 MB

    prep<<<P1_BLOCKS + PACK_BLOCKS, 256, 0, stream>>>(ei, M, W, Wres, Bp);
    gemm_part2<<<P1_BLOCKS + GEMM_BLOCKS, 256, 0, stream>>>(
        x, Bp, xw2, xres, attS, attD, asrc, adst, ei, M, binCnt, binStart, mid);
    agg2<<<NBINS, 512, 0, stream>>>(
        mid, binStart, binCnt, asrc, adst, xw2, xres, bias, out);
}

// Round 14
// 239.711 us; speedup vs baseline: 1.2562x; 1.2562x over previous
//
#include <hip/hip_runtime.h>
#include <math.h>

#define N_NODES 50000
#define N_EDGES 800000
#define IN_CH   256
#define OUT_CH  64
#define HEADS   4
#define NEG_SLOPE 0.2f
#define NCOLS   320           // W (256) || W_res (64)
#define NTILES  20            // NCOLS / 16
#define NKK     8             // IN_CH / 32
#define PACK_BLOCKS 40        // NKK*NTILES*64 / 256
#define GEMM_BLOCKS 782       // (N_NODES+63)/64
#define NBINS   782           // 64-dst bins (bin = dst>>6); 782*64 = 50048
#define P1_BLOCKS 256         // edge-partition blocks
#define EPB     3125          // edges per partition block = N_EDGES/256
#define SORT_CAP 1600         // max records per bin (mean 1023, sd 32)
// R14 schedule (4 dispatches). Laws: gemm ~65us/dispatch regardless of
// blocks (never chunk); fuse gemm with ONE lean (<65us) stage only — R13's
// in-block binscan fold was a ~40us serial chain and doubled the dispatch;
// binscan restored as its own cheap dispatch. agg2 (R13's scatter+aggregate
// fusion) kept, now ISOLATED for measurement.

typedef __attribute__((ext_vector_type(8))) short short8;
typedef __attribute__((ext_vector_type(4))) float f32x4;

__device__ __forceinline__ float lrelu(float v) {
    return v > 0.f ? v : NEG_SLOPE * v;
}
__device__ __forceinline__ unsigned bf16_rne(float f) {
    unsigned u = __float_as_uint(f);
    return (u + 0x7FFFu + ((u >> 16) & 1u)) >> 16;
}
__device__ __forceinline__ unsigned pack2(float lo, float hi) {
    return bf16_rne(lo) | (bf16_rne(hi) << 16);
}
__device__ __forceinline__ float bflo(unsigned u) { return __uint_as_float(u << 16); }
__device__ __forceinline__ float bfhi(unsigned u) { return __uint_as_float(u & 0xFFFF0000u); }
__device__ __forceinline__ short8 as_short8(uint4 u) {
    union { uint4 u4; short8 s8; } cv; cv.u4 = u; return cv.s8;
}

// ---------------------------------------------------------------------------
// D1 prep: fused independent halves.
//   blocks [0, P1_BLOCKS)        : histogram (lean shape, 3.1 KB LDS)
//   blocks [P1_BLOCKS,+PACK)     : pack_B
// ---------------------------------------------------------------------------
__global__ __launch_bounds__(256) void prep(
    const int* __restrict__ ei, int* __restrict__ M,
    const float* __restrict__ W, const float* __restrict__ Wres,
    uint4* __restrict__ Bp)
{
    __shared__ int lh[NBINS];
    const int t = threadIdx.x;

    if (blockIdx.x < P1_BLOCKS) {
        const int blk = blockIdx.x;
        for (int b = t; b < NBINS; b += 256) lh[b] = 0;
        __syncthreads();
        const int e0 = blk * EPB;
        #pragma unroll
        for (int r = 0; r < 13; ++r) {
            const int idx = (r << 8) + t;
            if (idx < EPB)
                atomicAdd(&lh[ei[N_EDGES + e0 + idx] >> 6], 1);
        }
        __syncthreads();
        for (int b = t; b < NBINS; b += 256)
            M[(size_t)b * P1_BLOCKS + blk] = lh[b];
        return;
    }

    const int idx  = (blockIdx.x - P1_BLOCKS) * 256 + t;   // 0..10239
    const int kk   = idx / (NTILES * 64);
    const int rem  = idx - kk * (NTILES * 64);
    const int tt   = rem >> 6;
    const int lane = rem & 63;
    const int colL = lane & 15, quad = lane >> 4;
    const int col  = tt * 16 + colL;
    const int k0   = kk * 32 + quad * 8;
    float v[8];
    #pragma unroll
    for (int j = 0; j < 8; ++j) {
        const int k = k0 + j;
        v[j] = (col < IN_CH) ? W[(size_t)k * IN_CH + col]
                             : Wres[(size_t)k * OUT_CH + (col - IN_CH)];
    }
    uint4 u;
    u.x = pack2(v[0], v[1]); u.y = pack2(v[2], v[3]);
    u.z = pack2(v[4], v[5]); u.w = pack2(v[6], v[7]);
    Bp[(kk * NTILES + tt) * 64 + lane] = u;
}

// ---------------------------------------------------------------------------
// D2 binscan_M (R12-proven, ~6us): one block per bin; exclusive-scan
// M[b][0..255] in place, total -> binCnt[b]. 782 blocks.
// ---------------------------------------------------------------------------
__global__ __launch_bounds__(256) void binscan_M(
    int* __restrict__ M, int* __restrict__ binCnt)
{
    __shared__ int ws[4];
    const int t = threadIdx.x, lane = t & 63, w = t >> 6;
    const int b = blockIdx.x;
    const int v = M[(size_t)b * P1_BLOCKS + t];
    int sc = v;
    #pragma unroll
    for (int off = 1; off < 64; off <<= 1) {
        const int n = __shfl_up(sc, off);
        if (lane >= off) sc += n;
    }
    if (lane == 63) ws[w] = sc;
    __syncthreads();
    int prefix = 0;
    for (int j = 0; j < w; ++j) prefix += ws[j];
    M[(size_t)b * P1_BLOCKS + t] = prefix + sc - v;
    if (t == 255) binCnt[b] = prefix + sc;
}

// ---------------------------------------------------------------------------
// gemm_body: R6/R10's proven 64-row/256-thr MFMA transform + fused logits.
// Wave wv owns col-tiles {wv,4+wv,8+wv,12+wv,16+wv} over 4 row-groups.
// ---------------------------------------------------------------------------
__device__ __forceinline__ void gemm_body(
    const int n0, const float* __restrict__ x, const uint4* __restrict__ Bp,
    uint2* __restrict__ xw2, float* __restrict__ xres,
    const float* __restrict__ attS, const float* __restrict__ attD,
    float* __restrict__ asrc, float* __restrict__ adst,
    uint4* Alds, float (*logS)[HEADS], float (*logD)[HEADS])
{
    const int tid = threadIdx.x;

    logS[tid >> 2][tid & 3] = 0.f;
    logD[tid >> 2][tid & 3] = 0.f;

    #pragma unroll
    for (int i = 0; i < 8; ++i) {
        const int e    = i * 256 + tid;
        const int g    = e >> 9;
        const int kk   = (e >> 6) & 7;
        const int lane = e & 63;
        const int cL   = lane & 15, qd = lane >> 4;
        const int row  = n0 + g * 16 + cL;
        const int k0   = kk * 32 + qd * 8;
        uint4 u = make_uint4(0u, 0u, 0u, 0u);
        if (row < N_NODES) {
            const float4 a = *reinterpret_cast<const float4*>(x + (size_t)row * IN_CH + k0);
            const float4 b = *reinterpret_cast<const float4*>(x + (size_t)row * IN_CH + k0 + 4);
            u.x = pack2(a.x, a.y); u.y = pack2(a.z, a.w);
            u.z = pack2(b.x, b.y); u.w = pack2(b.z, b.w);
        }
        Alds[(g * NKK + kk) * 64 + lane] = u;
    }
    __syncthreads();

    const int lane = tid & 63;
    const int wv   = tid >> 6;
    const int colL = lane & 15, quad = lane >> 4;

    f32x4 acc[4][5];
    #pragma unroll
    for (int rg = 0; rg < 4; ++rg)
        #pragma unroll
        for (int j = 0; j < 5; ++j) acc[rg][j] = (f32x4){0.f, 0.f, 0.f, 0.f};

    for (int kk = 0; kk < NKK; ++kk) {
        uint4 bu[5];
        #pragma unroll
        for (int j = 0; j < 5; ++j)
            bu[j] = Bp[(kk * NTILES + j * 4 + wv) * 64 + lane];
        #pragma unroll
        for (int rg = 0; rg < 4; ++rg) {
            const short8 a = as_short8(Alds[(rg * NKK + kk) * 64 + lane]);
            #pragma unroll
            for (int j = 0; j < 5; ++j)
                acc[rg][j] = __builtin_amdgcn_mfma_f32_16x16x32_bf16(
                    a, as_short8(bu[j]), acc[rg][j], 0, 0, 0);
        }
    }

    #pragma unroll
    for (int rg = 0; rg < 4; ++rg) {
        #pragma unroll
        for (int r = 0; r < 4; ++r) {
            const int row = n0 + rg * 16 + quad * 4 + r;
            if (row < N_NODES) {
                xw2[(size_t)row * 64 + wv * 16 + colL] = make_uint2(
                    pack2(acc[rg][0][r], acc[rg][1][r]),
                    pack2(acc[rg][2][r], acc[rg][3][r]));
                xres[(size_t)row * OUT_CH + wv * 16 + colL] = acc[rg][4][r];
            }
        }
    }

    float aSr[HEADS], aDr[HEADS];
    #pragma unroll
    for (int h = 0; h < HEADS; ++h) {
        aSr[h] = attS[h * 64 + wv * 16 + colL];
        aDr[h] = attD[h * 64 + wv * 16 + colL];
    }
    #pragma unroll
    for (int rg = 0; rg < 4; ++rg) {
        #pragma unroll
        for (int h = 0; h < HEADS; ++h) {
            #pragma unroll
            for (int r = 0; r < 4; ++r) {
                float vS = acc[rg][h][r] * aSr[h];
                float vD = acc[rg][h][r] * aDr[h];
                #pragma unroll
                for (int m = 1; m < 16; m <<= 1) {      // stays within quad
                    vS += __shfl_xor(vS, m);
                    vD += __shfl_xor(vD, m);
                }
                if (colL == 0) {
                    atomicAdd(&logS[rg * 16 + quad * 4 + r][h], vS);
                    atomicAdd(&logD[rg * 16 + quad * 4 + r][h], vD);
                }
            }
        }
    }
    __syncthreads();
    {
        const int rl = tid >> 2, h = tid & 3;
        const int row = n0 + rl;
        if (row < N_NODES) {
            asrc[(size_t)row * HEADS + h] = logS[rl][h];
            adst[(size_t)row * HEADS + h] = logD[rl][h];
        }
    }
}

// ---------------------------------------------------------------------------
// D3 gemm_part (byte-identical to R12's 67us-measured version): fused —
// blocks [0,256) part_mid (reads SCANNED M + binCnt, inline 782-wide
// binStart scan over binCnt only — cheap; block 0 publishes binStart);
// blocks [256,+782) the FULL gemm. part (~40us) hides under gemm (~65us).
// ---------------------------------------------------------------------------
__global__ __launch_bounds__(256) void gemm_part(
    const float* __restrict__ x, const uint4* __restrict__ Bp,
    uint2* __restrict__ xw2, float* __restrict__ xres,
    const float* __restrict__ attS, const float* __restrict__ attD,
    float* __restrict__ asrc, float* __restrict__ adst,
    const int* __restrict__ ei, const int* __restrict__ M,
    const int* __restrict__ binCnt, int* __restrict__ binStart,
    unsigned* __restrict__ mid)
{
    __shared__ uint4 Alds[4 * NKK * 64];   // 32 KB (aliased by part branch)
    __shared__ float logS[64][HEADS];
    __shared__ float logD[64][HEADS];
    const int t = threadIdx.x, lane = t & 63, wv = t >> 6;

    if (blockIdx.x < P1_BLOCKS) {
        int* bc    = (int*)Alds;           // [782]
        int* bs    = bc + NBINS;           // [782]
        int* baseL = bs + NBINS;           // [782]
        int* lh    = baseL + NBINS;        // [782]
        int* ws    = lh + NBINS;           // [4]
        const int blk = blockIdx.x;

        for (int b = t; b < NBINS; b += 256) {
            bc[b] = binCnt[b];
            baseL[b] = M[(size_t)b * P1_BLOCKS + blk];
            lh[b] = 0;
        }
        __syncthreads();

        int carry = 0;
        for (int c = 0; c < 4; ++c) {
            const int i = (c << 8) + t;
            const int v = (i < NBINS) ? bc[i] : 0;
            int sc = v;
            #pragma unroll
            for (int o = 1; o < 64; o <<= 1) {
                const int n = __shfl_up(sc, o);
                if (lane >= o) sc += n;
            }
            if (lane == 63) ws[wv] = sc;
            __syncthreads();
            int prefix = 0;
            for (int j = 0; j < wv; ++j) prefix += ws[j];
            if (i < NBINS) bs[i] = carry + prefix + sc - v;
            carry += ws[0] + ws[1] + ws[2] + ws[3];
            __syncthreads();   // protect ws before next chunk rewrites it
        }
        for (int b = t; b < NBINS; b += 256) baseL[b] += bs[b];
        if (blk == 0)
            for (int b = t; b < NBINS; b += 256) binStart[b] = bs[b];
        __syncthreads();

        const int e0 = blk * EPB;
        #pragma unroll
        for (int r = 0; r < 13; ++r) {
            const int idx = (r << 8) + t;
            if (idx < EPB) {
                const int e = e0 + idx;
                const int d = ei[N_EDGES + e];
                const int b = d >> 6;
                const int pos = atomicAdd(&lh[b], 1);
                mid[baseL[b] + pos] = ((unsigned)(d & 63) << 17) | (unsigned)ei[e];
            }
        }
        return;
    }
    gemm_body((blockIdx.x - P1_BLOCKS) * 64,
              x, Bp, xw2, xres, attS, attD, asrc, adst, Alds, logS, logD);
}

// ---------------------------------------------------------------------------
// D4 agg2 (R13's fusion, now isolated): scatter + aggregate, one 512-thread
// block per 64-dst bin. Phase A: count, single-wave 64-scan, LDS-sort the
// ~1024 records into srt[] (no esrc global round-trip). Phase B: 8 waves x
// 8 dsts; per-dst gather body byte-identical to the 64.7us-measured
// aggregate (uniform-addr xw2 dwordx2 gather, fabric-bound).
// ---------------------------------------------------------------------------
__global__ __launch_bounds__(512) void agg2(
    const unsigned* __restrict__ mid, const int* __restrict__ binStart,
    const int* __restrict__ binCnt,
    const float* __restrict__ asrc, const float* __restrict__ adst,
    const uint2* __restrict__ xw2, const float* __restrict__ xres,
    const float* __restrict__ bias, float* __restrict__ out)
{
    __shared__ int c64[64];
    __shared__ int o64[64];
    __shared__ int srt[SORT_CAP];          // 6.4 KB
    __shared__ float4 wbuf[8][64];         // 8 KB
    __shared__ int    sbuf[8][64];         // 2 KB
    const int t = threadIdx.x, lane = t & 63, wv = t >> 6;   // wv 0..7
    const int b = blockIdx.x;
    const int base = binStart[b];
    const int n = binCnt[b];

    if (t < 64) c64[t] = 0;
    __syncthreads();

    for (int i = t; i < n; i += 512)
        atomicAdd(&c64[(int)(mid[base + i] >> 17)], 1);
    __syncthreads();

    if (t < 64) {                          // single-wave exclusive scan
        const int v = c64[t];
        int sc = v;
        #pragma unroll
        for (int o = 1; o < 64; o <<= 1) {
            const int nn = __shfl_up(sc, o);
            if (t >= o) sc += nn;
        }
        o64[t] = sc - v;
        c64[t] = 0;                        // reuse as running positions
    }
    __syncthreads();

    for (int i = t; i < n; i += 512) {
        const unsigned m = mid[base + i];
        const int dlo = (int)(m >> 17);
        const int pos = atomicAdd(&c64[dlo], 1);
        srt[o64[dlo] + pos] = (int)(m & 0x1FFFFu);
    }
    __syncthreads();                       // c64[dlo] == per-dst count again

    const char* xwB = (const char*)xw2;
    const int laneB = lane << 3;

    #pragma unroll 1
    for (int k = 0; k < 8; ++k) {
        const int dlo = wv * 8 + k;
        const int d = (b << 6) + dlo;
        if (d >= N_NODES) continue;        // tail bin
        const int off = o64[dlo];
        const int deg = c64[dlo];
        const float4 ad = *reinterpret_cast<const float4*>(adst + (size_t)d * 4);

        float dn0 = 0.f, dn1 = 0.f, dn2 = 0.f, dn3 = 0.f;
        float ac0 = 0.f, ac1 = 0.f, ac2 = 0.f, ac3 = 0.f;

        for (int bs0 = 0; bs0 < deg; bs0 += 64) {
            const int m = min(64, deg - bs0);
            if (lane < m) {
                const int s = srt[off + bs0 + lane];
                const float4 as = *reinterpret_cast<const float4*>(asrc + (size_t)s * 4);
                const float e0 = __expf(lrelu(as.x + ad.x));
                const float e1 = __expf(lrelu(as.y + ad.y));
                const float e2 = __expf(lrelu(as.z + ad.z));
                const float e3 = __expf(lrelu(as.w + ad.w));
                dn0 += e0; dn1 += e1; dn2 += e2; dn3 += e3;
                wbuf[wv][lane] = make_float4(e0, e1, e2, e3);
                sbuf[wv][lane] = s << 9;   // *512 B node row
            }
            int j = 0;
            for (; j + 4 <= m; j += 4) {
                uint2 v0 = *(const uint2*)(xwB + sbuf[wv][j]     + laneB);
                uint2 v1 = *(const uint2*)(xwB + sbuf[wv][j + 1] + laneB);
                uint2 v2 = *(const uint2*)(xwB + sbuf[wv][j + 2] + laneB);
                uint2 v3 = *(const uint2*)(xwB + sbuf[wv][j + 3] + laneB);
                {
                    const float4 w = wbuf[wv][j];
                    ac0 = fmaf(w.x, bflo(v0.x), ac0); ac1 = fmaf(w.y, bfhi(v0.x), ac1);
                    ac2 = fmaf(w.z, bflo(v0.y), ac2); ac3 = fmaf(w.w, bfhi(v0.y), ac3);
                }
                {
                    const float4 w = wbuf[wv][j + 1];
                    ac0 = fmaf(w.x, bflo(v1.x), ac0); ac1 = fmaf(w.y, bfhi(v1.x), ac1);
                    ac2 = fmaf(w.z, bflo(v1.y), ac2); ac3 = fmaf(w.w, bfhi(v1.y), ac3);
                }
                {
                    const float4 w = wbuf[wv][j + 2];
                    ac0 = fmaf(w.x, bflo(v2.x), ac0); ac1 = fmaf(w.y, bfhi(v2.x), ac1);
                    ac2 = fmaf(w.z, bflo(v2.y), ac2); ac3 = fmaf(w.w, bfhi(v2.y), ac3);
                }
                {
                    const float4 w = wbuf[wv][j + 3];
                    ac0 = fmaf(w.x, bflo(v3.x), ac0); ac1 = fmaf(w.y, bfhi(v3.x), ac1);
                    ac2 = fmaf(w.z, bflo(v3.y), ac2); ac3 = fmaf(w.w, bfhi(v3.y), ac3);
                }
            }
            for (; j < m; ++j) {
                const float4 w = wbuf[wv][j];
                const uint2 v = *(const uint2*)(xwB + sbuf[wv][j] + laneB);
                ac0 = fmaf(w.x, bflo(v.x), ac0);
                ac1 = fmaf(w.y, bfhi(v.x), ac1);
                ac2 = fmaf(w.z, bflo(v.y), ac2);
                ac3 = fmaf(w.w, bfhi(v.y), ac3);
            }
        }

        #pragma unroll
        for (int off2 = 32; off2 >= 1; off2 >>= 1) {
            dn0 += __shfl_xor(dn0, off2);
            dn1 += __shfl_xor(dn1, off2);
            dn2 += __shfl_xor(dn2, off2);
            dn3 += __shfl_xor(dn3, off2);
        }
        // self-loop
        const float4 asd = *reinterpret_cast<const float4*>(asrc + (size_t)d * 4);
        const float s0 = __expf(lrelu(asd.x + ad.x));
        const float s1 = __expf(lrelu(asd.y + ad.y));
        const float s2 = __expf(lrelu(asd.z + ad.z));
        const float s3 = __expf(lrelu(asd.w + ad.w));
        const uint2 u = xw2[(size_t)d * 64 + lane];
        ac0 = fmaf(s0, bflo(u.x), ac0); ac1 = fmaf(s1, bfhi(u.x), ac1);
        ac2 = fmaf(s2, bflo(u.y), ac2); ac3 = fmaf(s3, bfhi(u.y), ac3);
        const float i0 = 0.25f / (dn0 + s0);
        const float i1 = 0.25f / (dn1 + s1);
        const float i2 = 0.25f / (dn2 + s2);
        const float i3 = 0.25f / (dn3 + s3);
        const float v = ac0 * i0 + ac1 * i1 + ac2 * i2 + ac3 * i3
                      + bias[lane] + xres[(size_t)d * OUT_CH + lane];
        out[(size_t)d * OUT_CH + lane] = fmaxf(v, 0.f);
    }
}

extern "C" void kernel_launch(void* const* d_in, const int* in_sizes, int n_in,
                              void* d_out, int out_size, void* d_ws, size_t ws_size,
                              hipStream_t stream) {
    const float* x    = (const float*)d_in[0];
    const int*   ei   = (const int*)d_in[1];
    const float* W    = (const float*)d_in[2];
    const float* attS = (const float*)d_in[3];
    const float* attD = (const float*)d_in[4];
    const float* bias = (const float*)d_in[5];
    const float* Wres = (const float*)d_in[6];
    float* out = (float*)d_out;

    char* p = (char*)d_ws;
    uint4*    Bp      = (uint4*)p;    p += (size_t)NKK * NTILES * 64 * 16;  // 160 KB
    uint2*    xw2     = (uint2*)p;    p += (size_t)N_NODES * 64 * 8;        // 25.6 MB
    float*    xres    = (float*)p;    p += (size_t)N_NODES * OUT_CH * 4;    // 12.8 MB
    float*    asrc    = (float*)p;    p += (size_t)N_NODES * HEADS * 4;
    float*    adst    = (float*)p;    p += (size_t)N_NODES * HEADS * 4;
    int*      M       = (int*)p;      p += (size_t)NBINS * P1_BLOCKS * 4;   // 800 KB
    int*      binCnt  = (int*)p;      p += 1024 * 4;
    int*      binStart= (int*)p;      p += 1024 * 4;
    unsigned* mid     = (unsigned*)p; p += (size_t)N_EDGES * 4;             // 3.2 MB

    prep<<<P1_BLOCKS + PACK_BLOCKS, 256, 0, stream>>>(ei, M, W, Wres, Bp);
    binscan_M<<<NBINS, 256, 0, stream>>>(M, binCnt);
    gemm_part<<<P1_BLOCKS + GEMM_BLOCKS, 256, 0, stream>>>(
        x, Bp, xw2, xres, attS, attD, asrc, adst, ei, M, binCnt, binStart, mid);
    agg2<<<NBINS, 512, 0, stream>>>(
        mid, binStart, binCnt, asrc, adst, xw2, xres, bias, out);
}